// Round 3
// baseline (185.356 us; speedup 1.0000x reference)
//
#include <hip/hip_runtime.h>
#include <math.h>

#define TPB 256

typedef unsigned short u16;
typedef short bf16x8 __attribute__((ext_vector_type(8)));
typedef unsigned short u16x4 __attribute__((ext_vector_type(4)));
typedef float f32x4 __attribute__((ext_vector_type(4)));

__device__ __forceinline__ u16 f2bf(float x) {
    unsigned u = __float_as_uint(x);
    unsigned r = u + 0x7fffu + ((u >> 16) & 1u);
    return (u16)(r >> 16);
}
__device__ __forceinline__ float bf2f(u16 h) {
    return __uint_as_float(((unsigned)h) << 16);
}
// storage permutation within a 32-wide k chunk; flag=1: half-split layout, flag=0: identity
__device__ __forceinline__ int pos32(int kk, int flag) {
    return flag ? (((kk >> 2) & 3) * 8 + (kk >> 4) * 4 + (kk & 3)) : kk;
}

// ---------------- probe: determine MFMA A/B fragment k-mapping on device ----------------
__device__ __forceinline__ float probeA(int i, int k) { return (float)((i * 37 + k * 11) % 13 - 6); }
__device__ __forceinline__ float probeB(int k, int j) { return (float)((k * 7 + j * 29) % 11 - 5); }

__global__ void probe_kernel(int* flag) {
    int l = threadIdx.x;
    int col = l & 15;
    float ref[4];
    #pragma unroll
    for (int j = 0; j < 4; ++j) {
        int row = 4 * (l >> 4) + j;
        float s = 0.f;
        for (int k = 0; k < 32; ++k) s += probeA(row, k) * probeB(k, col);
        ref[j] = s;
    }
    f32x4 z = {0.f, 0.f, 0.f, 0.f};
    bf16x8 a, b;
    #pragma unroll
    for (int i = 0; i < 8; ++i) {  // layout A: half-split
        int k = 4 * (l >> 4) + (i & 3) + 16 * (i >> 2);
        a[i] = (short)f2bf(probeA(l & 15, k));
        b[i] = (short)f2bf(probeB(k, l & 15));
    }
    f32x4 dA = __builtin_amdgcn_mfma_f32_16x16x32_bf16(a, b, z, 0, 0, 0);
    bool okA = dA[0] == ref[0] && dA[1] == ref[1] && dA[2] == ref[2] && dA[3] == ref[3];
    #pragma unroll
    for (int i = 0; i < 8; ++i) {  // layout B: consecutive 8
        int k = 8 * (l >> 4) + i;
        a[i] = (short)f2bf(probeA(l & 15, k));
        b[i] = (short)f2bf(probeB(k, l & 15));
    }
    f32x4 dB = __builtin_amdgcn_mfma_f32_16x16x32_bf16(a, b, z, 0, 0, 0);
    bool okB = dB[0] == ref[0] && dB[1] == ref[1] && dB[2] == ref[2] && dB[3] == ref[3];
    int allA = __all(okA), allB = __all(okB);
    if (l == 0) *flag = allA ? 1 : (allB ? 0 : 1);
}

// ---------------- bias vectors r[i] = u_p[i]·w1, c[j] = u_c[j]·w2 ----------------
__global__ __launch_bounds__(TPB) void bias_kernel(
    const float* __restrict__ u_p, const float* __restrict__ u_c,
    const float* __restrict__ wa, float* __restrict__ r, float* __restrict__ c,
    int m, int n, int d) {
    int b = blockIdx.x;
    const float* src; const float* w; float* dst;
    if (b < m) { src = u_p + (size_t)b * d;       w = wa;     dst = r + b; }
    else       { src = u_c + (size_t)(b - m) * d; w = wa + d; dst = c + (b - m); }
    float acc = 0.f;
    for (int k4 = threadIdx.x; k4 < d / 4; k4 += TPB) {
        float4 a = ((const float4*)src)[k4];
        float4 ww = ((const float4*)w)[k4];
        acc += a.x * ww.x + a.y * ww.y + a.z * ww.z + a.w * ww.w;
    }
    __shared__ float red[TPB];
    red[threadIdx.x] = acc;
    __syncthreads();
    for (int s = TPB / 2; s > 0; s >>= 1) {
        if (threadIdx.x < s) red[threadIdx.x] += red[threadIdx.x + s];
        __syncthreads();
    }
    if (threadIdx.x == 0) *dst = red[0];
}

// ---------------- init S[i][j] = r[i] + c[j] ----------------
__global__ __launch_bounds__(TPB) void initS_kernel(
    const float* __restrict__ r, const float* __restrict__ c,
    float* __restrict__ S, int m, int n) {
    int q = blockIdx.x * TPB + threadIdx.x;
    int nq = n >> 2;
    if (q >= m * nq) return;
    int i = q / nq;
    int j = (q - i * nq) * 4;
    float ri = r[i];
    float4 cj = *(const float4*)(c + j);
    float4 o = {ri + cj.x, ri + cj.y, ri + cj.z, ri + cj.w};
    *(float4*)(S + (size_t)i * n + j) = o;
}

// ---------------- pre-convert: upw3 = u_p*w3 (hi/lo), uc (hi/lo), permuted k layout ----------------
__global__ __launch_bounds__(TPB) void convert_kernel(
    const float* __restrict__ up, const float* __restrict__ uc,
    const float* __restrict__ wa,
    u16* __restrict__ upw3_hi, u16* __restrict__ upw3_lo,
    u16* __restrict__ uc_hi, u16* __restrict__ uc_lo,
    const int* __restrict__ flagp, int m, int n, int d, int has_lo) {
    int fl = *flagp;
    const float* w3 = wa + 2 * d;
    int qup = m * (d / 4);
    int qtot = (m + n) * (d / 4);
    for (int q = blockIdx.x * TPB + threadIdx.x; q < qtot; q += gridDim.x * TPB) {
        if (q < qup) {
            int row = q / (d / 4);
            int k = (q % (d / 4)) * 4;
            float4 v = *(const float4*)(up + (size_t)row * d + k);
            float4 w = *(const float4*)(w3 + k);
            float p0 = v.x * w.x, p1 = v.y * w.y, p2 = v.z * w.z, p3 = v.w * w.w;
            int p = (k & ~31) + pos32(k & 31, fl);
            u16x4 hi = {f2bf(p0), f2bf(p1), f2bf(p2), f2bf(p3)};
            *(u16x4*)(upw3_hi + (size_t)row * d + p) = hi;
            if (has_lo) {
                u16x4 lo = {f2bf(p0 - bf2f(hi[0])), f2bf(p1 - bf2f(hi[1])),
                            f2bf(p2 - bf2f(hi[2])), f2bf(p3 - bf2f(hi[3]))};
                *(u16x4*)(upw3_lo + (size_t)row * d + p) = lo;
            }
        } else {
            int q2 = q - qup;
            int row = q2 / (d / 4);
            int k = (q2 % (d / 4)) * 4;
            float4 v = *(const float4*)(uc + (size_t)row * d + k);
            int p = (k & ~31) + pos32(k & 31, fl);
            u16x4 hi = {f2bf(v.x), f2bf(v.y), f2bf(v.z), f2bf(v.w)};
            *(u16x4*)(uc_hi + (size_t)row * d + p) = hi;
            if (has_lo) {
                u16x4 lo = {f2bf(v.x - bf2f(hi[0])), f2bf(v.y - bf2f(hi[1])),
                            f2bf(v.z - bf2f(hi[2])), f2bf(v.w - bf2f(hi[3]))};
                *(u16x4*)(uc_lo + (size_t)row * d + p) = lo;
            }
        }
    }
}

// ---------------- transpose: src[rows][d] f32 -> dst[d][rows] bf16, perm on row index ----------------
__global__ __launch_bounds__(TPB) void transpose_kernel(
    const float* __restrict__ src, u16* __restrict__ dst,
    const int* __restrict__ flagp, int rows, int d) {
    __shared__ float t[64 * 65];
    int fl = *flagp;
    int tid = threadIdx.x;
    int r0 = blockIdx.y * 64;
    int c0 = blockIdx.x * 64;
    #pragma unroll
    for (int it = 0; it < 4; ++it) {
        int rr = (tid >> 4) + it * 16;
        int cc = (tid & 15) * 4;
        float4 v = *(const float4*)(src + (size_t)(r0 + rr) * d + c0 + cc);
        t[(cc + 0) * 65 + rr] = v.x;
        t[(cc + 1) * 65 + rr] = v.y;
        t[(cc + 2) * 65 + rr] = v.z;
        t[(cc + 3) * 65 + rr] = v.w;
    }
    __syncthreads();
    #pragma unroll
    for (int it = 0; it < 2; ++it) {
        int id = tid + it * TPB;
        int kc = id >> 3;
        int s = id & 7;
        u16 outv[8];
        #pragma unroll
        for (int e = 0; e < 8; ++e) {
            int p = s * 8 + e;
            int jloc;
            if (fl) {
                int p5 = p & 31;
                jloc = 32 * (p >> 5) + 16 * ((p5 >> 2) & 1) + 4 * (p5 >> 3) + (p5 & 3);
            } else jloc = p;
            outv[e] = f2bf(t[kc * 65 + jloc]);
        }
        *(u16x4*)(dst + (size_t)(c0 + kc) * rows + r0 + s * 8) = *(u16x4*)&outv[0];
        *(u16x4*)(dst + (size_t)(c0 + kc) * rows + r0 + s * 8 + 4) = *(u16x4*)&outv[4];
    }
}

// ---------------- MFMA GEMM: S += upw3 @ uc^T, split-K over blockIdx.z, bf16x3 when HAS_LO ----------------
template <int HAS_LO>
__global__ __launch_bounds__(TPB) void gemmS_mfma(
    const u16* __restrict__ Ah, const u16* __restrict__ Al,
    const u16* __restrict__ Bh, const u16* __restrict__ Bl,
    float* __restrict__ S, int n, int d, int ksplit) {
    __shared__ u16 sm[4 * 4096];
    u16* sAh = sm; u16* sAl = sm + 4096; u16* sBh = sm + 8192; u16* sBl = sm + 12288;
    int tid = threadIdx.x;
    int lane = tid & 63, wave = tid >> 6;
    int wm = wave >> 1, wn = wave & 1;
    int lrow = lane & 15, g = lane >> 4;
    int i0 = blockIdx.y * 64, j0 = blockIdx.x * 64;
    int kchunk = d / ksplit;
    int kbeg = blockIdx.z * kchunk;
    f32x4 acc[2][2];
    #pragma unroll
    for (int a = 0; a < 2; ++a)
        #pragma unroll
        for (int b = 0; b < 2; ++b) acc[a][b] = (f32x4){0.f, 0.f, 0.f, 0.f};

    for (int k0 = kbeg; k0 < kbeg + kchunk; k0 += 64) {
        #pragma unroll
        for (int it = 0; it < 2; ++it) {
            int id = tid + it * TPB;
            int row = id >> 3, slot = id & 7;
            int boff = (row * 128 + slot * 16) ^ ((row & 7) << 4);
            *(int4*)((char*)sAh + boff) = *(const int4*)(Ah + (size_t)(i0 + row) * d + k0 + slot * 8);
            *(int4*)((char*)sBh + boff) = *(const int4*)(Bh + (size_t)(j0 + row) * d + k0 + slot * 8);
            if (HAS_LO) {
                *(int4*)((char*)sAl + boff) = *(const int4*)(Al + (size_t)(i0 + row) * d + k0 + slot * 8);
                *(int4*)((char*)sBl + boff) = *(const int4*)(Bl + (size_t)(j0 + row) * d + k0 + slot * 8);
            }
        }
        __syncthreads();
        #pragma unroll
        for (int kk = 0; kk < 2; ++kk) {
            bf16x8 afh[2], bfh[2], afl[2], bfl[2];
            #pragma unroll
            for (int mr = 0; mr < 2; ++mr) {
                int row = wm * 32 + mr * 16 + lrow;
                int boff = (row * 128 + kk * 64 + g * 16) ^ ((row & 7) << 4);
                afh[mr] = *(const bf16x8*)((const char*)sAh + boff);
                if (HAS_LO) afl[mr] = *(const bf16x8*)((const char*)sAl + boff);
            }
            #pragma unroll
            for (int nr = 0; nr < 2; ++nr) {
                int row = wn * 32 + nr * 16 + lrow;
                int boff = (row * 128 + kk * 64 + g * 16) ^ ((row & 7) << 4);
                bfh[nr] = *(const bf16x8*)((const char*)sBh + boff);
                if (HAS_LO) bfl[nr] = *(const bf16x8*)((const char*)sBl + boff);
            }
            #pragma unroll
            for (int mr = 0; mr < 2; ++mr)
                #pragma unroll
                for (int nr = 0; nr < 2; ++nr) {
                    acc[mr][nr] = __builtin_amdgcn_mfma_f32_16x16x32_bf16(afh[mr], bfh[nr], acc[mr][nr], 0, 0, 0);
                    if (HAS_LO) {
                        acc[mr][nr] = __builtin_amdgcn_mfma_f32_16x16x32_bf16(afh[mr], bfl[nr], acc[mr][nr], 0, 0, 0);
                        acc[mr][nr] = __builtin_amdgcn_mfma_f32_16x16x32_bf16(afl[mr], bfh[nr], acc[mr][nr], 0, 0, 0);
                    }
                }
        }
        __syncthreads();
    }
    int crow = (lane >> 4) * 4;
    int ccol = lane & 15;
    #pragma unroll
    for (int mr = 0; mr < 2; ++mr) {
        #pragma unroll
        for (int nr = 0; nr < 2; ++nr) {
            int jc = j0 + wn * 32 + nr * 16 + ccol;
            #pragma unroll
            for (int jr = 0; jr < 4; ++jr) {
                int i = i0 + wm * 32 + mr * 16 + crow + jr;
                unsafeAtomicAdd(&S[(size_t)i * n + jc], acc[mr][nr][jr]);
            }
        }
    }
}

// ---------------- row softmax stats ----------------
__global__ __launch_bounds__(TPB) void row_stats_kernel(
    const float* __restrict__ S, float* __restrict__ rm, float* __restrict__ inv_rs, int n) {
    int row = blockIdx.x;
    const float* p = S + (size_t)row * n;
    float v[8];
    int cnt = 0;
    float mx = -INFINITY;
    for (int t = threadIdx.x; t < n; t += TPB) {
        v[cnt] = p[t];
        mx = fmaxf(mx, v[cnt]);
        ++cnt;
    }
    __shared__ float red[TPB];
    red[threadIdx.x] = mx;
    __syncthreads();
    for (int s = TPB / 2; s > 0; s >>= 1) {
        if (threadIdx.x < s) red[threadIdx.x] = fmaxf(red[threadIdx.x], red[threadIdx.x + s]);
        __syncthreads();
    }
    float gm = red[0];
    __syncthreads();
    float sum = 0.f;
    for (int u = 0; u < cnt; ++u) sum += __expf(v[u] - gm);
    red[threadIdx.x] = sum;
    __syncthreads();
    for (int s = TPB / 2; s > 0; s >>= 1) {
        if (threadIdx.x < s) red[threadIdx.x] += red[threadIdx.x + s];
        __syncthreads();
    }
    if (threadIdx.x == 0) { rm[row] = gm; inv_rs[row] = 1.f / red[0]; }
}

// ---------------- column softmax stats ----------------
__global__ __launch_bounds__(TPB) void col_stats_partial(
    const float* __restrict__ S, float* __restrict__ pm, float* __restrict__ ps,
    int n, int rows_per) {
    int col = blockIdx.x * TPB + threadIdx.x;
    int r0 = blockIdx.y * rows_per;
    float mx = -INFINITY, s = 0.f;
    for (int i = 0; i < rows_per; ++i) {
        float v = S[(size_t)(r0 + i) * n + col];
        if (v <= mx) {
            s += __expf(v - mx);
        } else {
            s = s * __expf(mx - v) + 1.f;
            mx = v;
        }
    }
    pm[(size_t)blockIdx.y * n + col] = mx;
    ps[(size_t)blockIdx.y * n + col] = s;
}

__global__ __launch_bounds__(TPB) void col_stats_merge(
    const float* __restrict__ pm, const float* __restrict__ ps,
    float* __restrict__ cm, float* __restrict__ inv_cs, int n, int chunks) {
    int col = blockIdx.x * TPB + threadIdx.x;
    float mx = -INFINITY;
    for (int c = 0; c < chunks; ++c) mx = fmaxf(mx, pm[(size_t)c * n + col]);
    float s = 0.f;
    for (int c = 0; c < chunks; ++c) s += ps[(size_t)c * n + col] * __expf(pm[(size_t)c * n + col] - mx);
    cm[col] = mx;
    inv_cs[col] = 1.f / s;
}

// ---------------- MFMA GEMM: a_alpha += softmax_row(S) @ u_c, split over j (blockIdx.z) ----------------
__global__ __launch_bounds__(TPB) void aalpha_mfma(
    const float* __restrict__ S, const float* __restrict__ rm, const float* __restrict__ irs,
    const u16* __restrict__ ucT, float* __restrict__ aalpha,
    const int* __restrict__ flagp, int m, int n, int d, int jsplit) {
    __shared__ u16 sA[4096];
    __shared__ u16 sB[4096];
    int fl = *flagp;
    int tid = threadIdx.x;
    int lane = tid & 63, wave = tid >> 6;
    int wm = wave >> 1, wn = wave & 1;
    int lrow = lane & 15, g = lane >> 4;
    int i0 = blockIdx.y * 64, kc0 = blockIdx.x * 64;
    int jchunk = n / jsplit;
    int jbeg = blockIdx.z * jchunk;
    f32x4 acc[2][2];
    #pragma unroll
    for (int a = 0; a < 2; ++a)
        #pragma unroll
        for (int b = 0; b < 2; ++b) acc[a][b] = (f32x4){0.f, 0.f, 0.f, 0.f};

    for (int j0 = jbeg; j0 < jbeg + jchunk; j0 += 64) {
        #pragma unroll
        for (int it = 0; it < 4; ++it) {
            int id = tid + it * TPB;
            int row = id >> 4;
            int cq = id & 15;
            float4 sv = *(const float4*)(S + (size_t)(i0 + row) * n + j0 + cq * 4);
            float mi = rm[i0 + row], sc = irs[i0 + row];
            int p = fl ? (32 * (cq >> 3) + (cq & 3) * 8 + ((cq >> 2) & 1) * 4) : cq * 4;
            int boff = (row * 128 + p * 2) ^ ((row & 7) << 4);
            u16x4 pv = {f2bf(__expf(sv.x - mi) * sc), f2bf(__expf(sv.y - mi) * sc),
                        f2bf(__expf(sv.z - mi) * sc), f2bf(__expf(sv.w - mi) * sc)};
            *(u16x4*)((char*)sA + boff) = pv;
        }
        #pragma unroll
        for (int it = 0; it < 2; ++it) {
            int id = tid + it * TPB;
            int row = id >> 3, slot = id & 7;
            int boff = (row * 128 + slot * 16) ^ ((row & 7) << 4);
            *(int4*)((char*)sB + boff) = *(const int4*)(ucT + (size_t)(kc0 + row) * n + j0 + slot * 8);
        }
        __syncthreads();
        #pragma unroll
        for (int kk = 0; kk < 2; ++kk) {
            bf16x8 av[2], bv[2];
            #pragma unroll
            for (int mr = 0; mr < 2; ++mr) {
                int row = wm * 32 + mr * 16 + lrow;
                int boff = (row * 128 + kk * 64 + g * 16) ^ ((row & 7) << 4);
                av[mr] = *(const bf16x8*)((const char*)sA + boff);
            }
            #pragma unroll
            for (int nr = 0; nr < 2; ++nr) {
                int row = wn * 32 + nr * 16 + lrow;
                int boff = (row * 128 + kk * 64 + g * 16) ^ ((row & 7) << 4);
                bv[nr] = *(const bf16x8*)((const char*)sB + boff);
            }
            #pragma unroll
            for (int mr = 0; mr < 2; ++mr)
                #pragma unroll
                for (int nr = 0; nr < 2; ++nr)
                    acc[mr][nr] = __builtin_amdgcn_mfma_f32_16x16x32_bf16(av[mr], bv[nr], acc[mr][nr], 0, 0, 0);
        }
        __syncthreads();
    }
    int crow = (lane >> 4) * 4;
    int ccol = lane & 15;
    #pragma unroll
    for (int mr = 0; mr < 2; ++mr)
        #pragma unroll
        for (int nr = 0; nr < 2; ++nr) {
            int kc = kc0 + wn * 32 + nr * 16 + ccol;
            #pragma unroll
            for (int jr = 0; jr < 4; ++jr) {
                int i = i0 + wm * 32 + mr * 16 + crow + jr;
                unsafeAtomicAdd(&aalpha[(size_t)i * d + kc], acc[mr][nr][jr]);
            }
        }
}

// ---------------- MFMA GEMM: a_beta += softmax_col(S)^T @ u_p, split over i (blockIdx.z) ----------------
__global__ __launch_bounds__(TPB) void abeta_mfma(
    const float* __restrict__ S, const float* __restrict__ cm, const float* __restrict__ ics,
    const u16* __restrict__ upT, float* __restrict__ abeta,
    const int* __restrict__ flagp, int m, int n, int d, int isplit) {
    __shared__ u16 sA[4096];
    __shared__ u16 sB[4096];
    int fl = *flagp;
    int tid = threadIdx.x;
    int lane = tid & 63, wave = tid >> 6;
    int wm = wave >> 1, wn = wave & 1;
    int lrow = lane & 15, g = lane >> 4;
    int jb0 = blockIdx.y * 64, kc0 = blockIdx.x * 64;
    int ichunk = m / isplit;
    int ibeg = blockIdx.z * ichunk;
    f32x4 acc[2][2];
    #pragma unroll
    for (int a = 0; a < 2; ++a)
        #pragma unroll
        for (int b = 0; b < 2; ++b) acc[a][b] = (f32x4){0.f, 0.f, 0.f, 0.f};

    for (int i0 = ibeg; i0 < ibeg + ichunk; i0 += 64) {
        #pragma unroll
        for (int it = 0; it < 4; ++it) {
            int id = tid + it * TPB;
            int r = id >> 4;
            int cq = id & 15;
            float4 sv = *(const float4*)(S + (size_t)(i0 + r) * n + jb0 + cq * 4);
            float4 mj = *(const float4*)(cm + jb0 + cq * 4);
            float4 sj = *(const float4*)(ics + jb0 + cq * 4);
            int pi;
            if (fl) { int r5 = r & 31; pi = 32 * (r >> 5) + ((r5 >> 2) & 3) * 8 + (r5 >> 4) * 4 + (r5 & 3); }
            else pi = r;
            u16 v0 = f2bf(__expf(sv.x - mj.x) * sj.x);
            u16 v1 = f2bf(__expf(sv.y - mj.y) * sj.y);
            u16 v2 = f2bf(__expf(sv.z - mj.z) * sj.z);
            u16 v3 = f2bf(__expf(sv.w - mj.w) * sj.w);
            int j = cq * 4;
            *(u16*)((char*)sA + ((((j + 0) * 128) + pi * 2) ^ (((j + 0) & 7) << 4))) = v0;
            *(u16*)((char*)sA + ((((j + 1) * 128) + pi * 2) ^ (((j + 1) & 7) << 4))) = v1;
            *(u16*)((char*)sA + ((((j + 2) * 128) + pi * 2) ^ (((j + 2) & 7) << 4))) = v2;
            *(u16*)((char*)sA + ((((j + 3) * 128) + pi * 2) ^ (((j + 3) & 7) << 4))) = v3;
        }
        #pragma unroll
        for (int it = 0; it < 2; ++it) {
            int id = tid + it * TPB;
            int row = id >> 3, slot = id & 7;
            int boff = (row * 128 + slot * 16) ^ ((row & 7) << 4);
            *(int4*)((char*)sB + boff) = *(const int4*)(upT + (size_t)(kc0 + row) * m + i0 + slot * 8);
        }
        __syncthreads();
        #pragma unroll
        for (int kk = 0; kk < 2; ++kk) {
            bf16x8 av[2], bv[2];
            #pragma unroll
            for (int mr = 0; mr < 2; ++mr) {
                int row = wm * 32 + mr * 16 + lrow;
                int boff = (row * 128 + kk * 64 + g * 16) ^ ((row & 7) << 4);
                av[mr] = *(const bf16x8*)((const char*)sA + boff);
            }
            #pragma unroll
            for (int nr = 0; nr < 2; ++nr) {
                int row = wn * 32 + nr * 16 + lrow;
                int boff = (row * 128 + kk * 64 + g * 16) ^ ((row & 7) << 4);
                bv[nr] = *(const bf16x8*)((const char*)sB + boff);
            }
            #pragma unroll
            for (int mr = 0; mr < 2; ++mr)
                #pragma unroll
                for (int nr = 0; nr < 2; ++nr)
                    acc[mr][nr] = __builtin_amdgcn_mfma_f32_16x16x32_bf16(av[mr], bv[nr], acc[mr][nr], 0, 0, 0);
        }
        __syncthreads();
    }
    int crow = (lane >> 4) * 4;
    int ccol = lane & 15;
    #pragma unroll
    for (int mr = 0; mr < 2; ++mr)
        #pragma unroll
        for (int nr = 0; nr < 2; ++nr) {
            int kc = kc0 + wn * 32 + nr * 16 + ccol;
            #pragma unroll
            for (int jr = 0; jr < 4; ++jr) {
                int j = jb0 + wm * 32 + mr * 16 + crow + jr;
                unsafeAtomicAdd(&abeta[(size_t)j * d + kc], acc[mr][nr][jr]);
            }
        }
}

// ---------------- fused final dot, stage 1 ----------------
__global__ __launch_bounds__(TPB) void final_stage1(
    const float* __restrict__ u_p, const float* __restrict__ u_c,
    const float* __restrict__ aalpha, const float* __restrict__ abeta,
    const float* __restrict__ W, float* __restrict__ partials, int n, int d) {
    size_t total = (size_t)n * d / 4;
    float acc = 0.f;
    for (size_t q = (size_t)blockIdx.x * TPB + threadIdx.x; q < total;
         q += (size_t)gridDim.x * TPB) {
        size_t e = q * 4;
        int i = (int)(e / d);
        int k = (int)(e % d);
        size_t base = (size_t)i * d + k;
        float4 up = *(const float4*)(u_p + base);
        float4 aa = *(const float4*)(aalpha + base);
        float4 uc = *(const float4*)(u_c + base);
        float4 ab = *(const float4*)(abeta + base);
        const float* wr = W + (size_t)i * 4 * d;
        float4 w0 = *(const float4*)(wr + k);
        float4 w1 = *(const float4*)(wr + d + k);
        float4 w2 = *(const float4*)(wr + 2 * d + k);
        float4 w3 = *(const float4*)(wr + 3 * d + k);
        acc += up.x * w0.x + aa.x * (w1.x + up.x * w2.x) + uc.x * ab.x * w3.x;
        acc += up.y * w0.y + aa.y * (w1.y + up.y * w2.y) + uc.y * ab.y * w3.y;
        acc += up.z * w0.z + aa.z * (w1.z + up.z * w2.z) + uc.z * ab.z * w3.z;
        acc += up.w * w0.w + aa.w * (w1.w + up.w * w2.w) + uc.w * ab.w * w3.w;
    }
    __shared__ float red[TPB];
    red[threadIdx.x] = acc;
    __syncthreads();
    for (int s = TPB / 2; s > 0; s >>= 1) {
        if (threadIdx.x < s) red[threadIdx.x] += red[threadIdx.x + s];
        __syncthreads();
    }
    if (threadIdx.x == 0) partials[blockIdx.x] = red[0];
}

__global__ __launch_bounds__(TPB) void final_stage2(
    const float* __restrict__ partials, int np, const float* __restrict__ bias,
    float* __restrict__ out) {
    double acc = 0.0;
    for (int t = threadIdx.x; t < np; t += TPB) acc += (double)partials[t];
    __shared__ double red[TPB];
    red[threadIdx.x] = acc;
    __syncthreads();
    for (int s = TPB / 2; s > 0; s >>= 1) {
        if (threadIdx.x < s) red[threadIdx.x] += red[threadIdx.x + s];
        __syncthreads();
    }
    if (threadIdx.x == 0) {
        double v = red[0] + (double)bias[0];
        out[0] = (float)(v > 0.0 ? v : 0.0);
    }
}

extern "C" void kernel_launch(void* const* d_in, const int* in_sizes, int n_in,
                              void* d_out, int out_size, void* d_ws, size_t ws_size,
                              hipStream_t stream) {
    const float* u_p = (const float*)d_in[0];
    const float* u_c = (const float*)d_in[1];
    const float* w_a = (const float*)d_in[2];
    const float* ffn_w = (const float*)d_in[3];
    const float* ffn_b = (const float*)d_in[4];
    float* out = (float*)d_out;

    int d = in_sizes[2] / 3;   // 2048
    int m = in_sizes[0] / d;   // 1024
    int n = in_sizes[1] / d;   // 1024
    const int CHUNKS = 64;
    const int NBLK_FINAL = 2048;
    const int KSPLIT = 4;      // gemmS:   1024 blocks = 4/CU
    const int JSPLIT = 2;      // aalpha:  1024 blocks = 4/CU
    const int ISPLIT = 2;      // abeta:   1024 blocks = 4/CU

    size_t md = (size_t)m * d, nd = (size_t)n * d, mn = (size_t)m * n;

    float* ws = (float*)d_ws;
    float* r = ws;                      // m
    float* c = r + m;                   // n
    float* rm = c + n;                  // m
    float* inv_rs = rm + m;             // m
    float* cm = inv_rs + m;             // n
    float* inv_cs = cm + n;             // n
    float* pm = inv_cs + n;             // CHUNKS*n
    float* ps = pm + (size_t)CHUNKS * n;
    float* partials = ps + (size_t)CHUNKS * n;  // NBLK_FINAL
    int* flagp = (int*)(partials + NBLK_FINAL);
    float* S = (float*)(flagp + 16);
    float* aalpha = S + mn;
    float* abeta = aalpha + md;
    u16* upw3_hi = (u16*)(abeta + nd);
    u16* uc_hi = upw3_hi + md;
    u16* ucT_hi = uc_hi + nd;
    u16* upT_hi = ucT_hi + nd;
    u16* upw3_lo = upT_hi + md;
    u16* uc_lo = upw3_lo + md;
    size_t need_full = (size_t)((char*)(uc_lo + nd) - (char*)d_ws);
    int has_lo = ws_size >= need_full ? 1 : 0;

    // zero the atomic-accumulated outputs (aalpha, abeta are contiguous)
    hipMemsetAsync(aalpha, 0, (md + nd) * sizeof(float), stream);

    probe_kernel<<<1, 64, 0, stream>>>(flagp);
    bias_kernel<<<m + n, TPB, 0, stream>>>(u_p, u_c, w_a, r, c, m, n, d);
    convert_kernel<<<2048, TPB, 0, stream>>>(u_p, u_c, w_a, upw3_hi, upw3_lo,
                                             uc_hi, uc_lo, flagp, m, n, d, has_lo);
    dim3 gtc(d / 64, n / 64);
    transpose_kernel<<<gtc, TPB, 0, stream>>>(u_c, ucT_hi, flagp, n, d);
    dim3 gtp(d / 64, m / 64);
    transpose_kernel<<<gtp, TPB, 0, stream>>>(u_p, upT_hi, flagp, m, d);

    initS_kernel<<<(m * (n / 4) + TPB - 1) / TPB, TPB, 0, stream>>>(r, c, S, m, n);

    dim3 gS(n / 64, m / 64, KSPLIT);
    if (has_lo)
        gemmS_mfma<1><<<gS, TPB, 0, stream>>>(upw3_hi, upw3_lo, uc_hi, uc_lo, S, n, d, KSPLIT);
    else
        gemmS_mfma<0><<<gS, TPB, 0, stream>>>(upw3_hi, upw3_lo, uc_hi, uc_lo, S, n, d, KSPLIT);

    row_stats_kernel<<<m, TPB, 0, stream>>>(S, rm, inv_rs, n);
    dim3 gCP(n / TPB, CHUNKS);
    col_stats_partial<<<gCP, TPB, 0, stream>>>(S, pm, ps, n, m / CHUNKS);
    col_stats_merge<<<n / TPB, TPB, 0, stream>>>(pm, ps, cm, inv_cs, n, CHUNKS);

    dim3 gA(d / 64, m / 64, JSPLIT);
    aalpha_mfma<<<gA, TPB, 0, stream>>>(S, rm, inv_rs, ucT_hi, aalpha, flagp, m, n, d, JSPLIT);
    dim3 gB(d / 64, n / 64, ISPLIT);
    abeta_mfma<<<gB, TPB, 0, stream>>>(S, cm, inv_cs, upT_hi, abeta, flagp, m, n, d, ISPLIT);

    final_stage1<<<NBLK_FINAL, TPB, 0, stream>>>(u_p, u_c, aalpha, abeta, ffn_w,
                                                 partials, n, d);
    final_stage2<<<1, TPB, 0, stream>>>(partials, NBLK_FINAL, ffn_b, out);

    (void)out_size; (void)n_in;
}

// Round 4
// 168.605 us; speedup vs baseline: 1.0994x; 1.0994x over previous
//
#include <hip/hip_runtime.h>
#include <math.h>

#define TPB 256

typedef unsigned short u16;
typedef short bf16x8 __attribute__((ext_vector_type(8)));
typedef unsigned short u16x4 __attribute__((ext_vector_type(4)));
typedef float f32x4 __attribute__((ext_vector_type(4)));

__device__ __forceinline__ u16 f2bf(float x) {
    unsigned u = __float_as_uint(x);
    unsigned r = u + 0x7fffu + ((u >> 16) & 1u);
    return (u16)(r >> 16);
}
__device__ __forceinline__ float bf2f(u16 h) {
    return __uint_as_float(((unsigned)h) << 16);
}
// storage permutation within a 32-wide k chunk; flag=1: half-split layout, flag=0: identity
__device__ __forceinline__ int pos32(int kk, int flag) {
    return flag ? (((kk >> 2) & 3) * 8 + (kk >> 4) * 4 + (kk & 3)) : kk;
}

// ---------------- probe: determine MFMA A/B fragment k-mapping on device ----------------
__device__ __forceinline__ float probeA(int i, int k) { return (float)((i * 37 + k * 11) % 13 - 6); }
__device__ __forceinline__ float probeB(int k, int j) { return (float)((k * 7 + j * 29) % 11 - 5); }

__global__ void probe_kernel(int* flag) {
    int l = threadIdx.x;
    int col = l & 15;
    float ref[4];
    #pragma unroll
    for (int j = 0; j < 4; ++j) {
        int row = 4 * (l >> 4) + j;
        float s = 0.f;
        for (int k = 0; k < 32; ++k) s += probeA(row, k) * probeB(k, col);
        ref[j] = s;
    }
    f32x4 z = {0.f, 0.f, 0.f, 0.f};
    bf16x8 a, b;
    #pragma unroll
    for (int i = 0; i < 8; ++i) {  // layout A: half-split
        int k = 4 * (l >> 4) + (i & 3) + 16 * (i >> 2);
        a[i] = (short)f2bf(probeA(l & 15, k));
        b[i] = (short)f2bf(probeB(k, l & 15));
    }
    f32x4 dA = __builtin_amdgcn_mfma_f32_16x16x32_bf16(a, b, z, 0, 0, 0);
    bool okA = dA[0] == ref[0] && dA[1] == ref[1] && dA[2] == ref[2] && dA[3] == ref[3];
    #pragma unroll
    for (int i = 0; i < 8; ++i) {  // layout B: consecutive 8
        int k = 8 * (l >> 4) + i;
        a[i] = (short)f2bf(probeA(l & 15, k));
        b[i] = (short)f2bf(probeB(k, l & 15));
    }
    f32x4 dB = __builtin_amdgcn_mfma_f32_16x16x32_bf16(a, b, z, 0, 0, 0);
    bool okB = dB[0] == ref[0] && dB[1] == ref[1] && dB[2] == ref[2] && dB[3] == ref[3];
    int allA = __all(okA), allB = __all(okB);
    if (l == 0) *flag = allA ? 1 : (allB ? 0 : 1);
}

// ---------------- bias vectors r[i] = u_p[i]·w1, c[j] = u_c[j]·w2 ----------------
__global__ __launch_bounds__(TPB) void bias_kernel(
    const float* __restrict__ u_p, const float* __restrict__ u_c,
    const float* __restrict__ wa, float* __restrict__ r, float* __restrict__ c,
    int m, int n, int d) {
    int b = blockIdx.x;
    const float* src; const float* w; float* dst;
    if (b < m) { src = u_p + (size_t)b * d;       w = wa;     dst = r + b; }
    else       { src = u_c + (size_t)(b - m) * d; w = wa + d; dst = c + (b - m); }
    float acc = 0.f;
    for (int k4 = threadIdx.x; k4 < d / 4; k4 += TPB) {
        float4 a = ((const float4*)src)[k4];
        float4 ww = ((const float4*)w)[k4];
        acc += a.x * ww.x + a.y * ww.y + a.z * ww.z + a.w * ww.w;
    }
    __shared__ float red[TPB];
    red[threadIdx.x] = acc;
    __syncthreads();
    for (int s = TPB / 2; s > 0; s >>= 1) {
        if (threadIdx.x < s) red[threadIdx.x] += red[threadIdx.x + s];
        __syncthreads();
    }
    if (threadIdx.x == 0) *dst = red[0];
}

// ---------------- init S[i][j] = r[i] + c[j] ----------------
__global__ __launch_bounds__(TPB) void initS_kernel(
    const float* __restrict__ r, const float* __restrict__ c,
    float* __restrict__ S, int m, int n) {
    int q = blockIdx.x * TPB + threadIdx.x;
    int nq = n >> 2;
    if (q >= m * nq) return;
    int i = q / nq;
    int j = (q - i * nq) * 4;
    float ri = r[i];
    float4 cj = *(const float4*)(c + j);
    float4 o = {ri + cj.x, ri + cj.y, ri + cj.z, ri + cj.w};
    *(float4*)(S + (size_t)i * n + j) = o;
}

// ---------------- pre-convert: upw3 = u_p*w3 (hi/lo), uc (hi/lo), permuted k layout ----------------
__global__ __launch_bounds__(TPB) void convert_kernel(
    const float* __restrict__ up, const float* __restrict__ uc,
    const float* __restrict__ wa,
    u16* __restrict__ upw3_hi, u16* __restrict__ upw3_lo,
    u16* __restrict__ uc_hi, u16* __restrict__ uc_lo,
    const int* __restrict__ flagp, int m, int n, int d, int has_lo) {
    int fl = *flagp;
    const float* w3 = wa + 2 * d;
    int qup = m * (d / 4);
    int qtot = (m + n) * (d / 4);
    for (int q = blockIdx.x * TPB + threadIdx.x; q < qtot; q += gridDim.x * TPB) {
        if (q < qup) {
            int row = q / (d / 4);
            int k = (q % (d / 4)) * 4;
            float4 v = *(const float4*)(up + (size_t)row * d + k);
            float4 w = *(const float4*)(w3 + k);
            float p0 = v.x * w.x, p1 = v.y * w.y, p2 = v.z * w.z, p3 = v.w * w.w;
            int p = (k & ~31) + pos32(k & 31, fl);
            u16x4 hi = {f2bf(p0), f2bf(p1), f2bf(p2), f2bf(p3)};
            *(u16x4*)(upw3_hi + (size_t)row * d + p) = hi;
            if (has_lo) {
                u16x4 lo = {f2bf(p0 - bf2f(hi[0])), f2bf(p1 - bf2f(hi[1])),
                            f2bf(p2 - bf2f(hi[2])), f2bf(p3 - bf2f(hi[3]))};
                *(u16x4*)(upw3_lo + (size_t)row * d + p) = lo;
            }
        } else {
            int q2 = q - qup;
            int row = q2 / (d / 4);
            int k = (q2 % (d / 4)) * 4;
            float4 v = *(const float4*)(uc + (size_t)row * d + k);
            int p = (k & ~31) + pos32(k & 31, fl);
            u16x4 hi = {f2bf(v.x), f2bf(v.y), f2bf(v.z), f2bf(v.w)};
            *(u16x4*)(uc_hi + (size_t)row * d + p) = hi;
            if (has_lo) {
                u16x4 lo = {f2bf(v.x - bf2f(hi[0])), f2bf(v.y - bf2f(hi[1])),
                            f2bf(v.z - bf2f(hi[2])), f2bf(v.w - bf2f(hi[3]))};
                *(u16x4*)(uc_lo + (size_t)row * d + p) = lo;
            }
        }
    }
}

// ---------------- transpose: src[rows][d] f32 -> dst[d][rows] bf16, perm on row index ----------------
__global__ __launch_bounds__(TPB) void transpose_kernel(
    const float* __restrict__ src, u16* __restrict__ dst,
    const int* __restrict__ flagp, int rows, int d) {
    __shared__ float t[64 * 65];
    int fl = *flagp;
    int tid = threadIdx.x;
    int r0 = blockIdx.y * 64;
    int c0 = blockIdx.x * 64;
    #pragma unroll
    for (int it = 0; it < 4; ++it) {
        int rr = (tid >> 4) + it * 16;
        int cc = (tid & 15) * 4;
        float4 v = *(const float4*)(src + (size_t)(r0 + rr) * d + c0 + cc);
        t[(cc + 0) * 65 + rr] = v.x;
        t[(cc + 1) * 65 + rr] = v.y;
        t[(cc + 2) * 65 + rr] = v.z;
        t[(cc + 3) * 65 + rr] = v.w;
    }
    __syncthreads();
    #pragma unroll
    for (int it = 0; it < 2; ++it) {
        int id = tid + it * TPB;
        int kc = id >> 3;
        int s = id & 7;
        u16 outv[8];
        #pragma unroll
        for (int e = 0; e < 8; ++e) {
            int p = s * 8 + e;
            int jloc;
            if (fl) {
                int p5 = p & 31;
                jloc = 32 * (p >> 5) + 16 * ((p5 >> 2) & 1) + 4 * (p5 >> 3) + (p5 & 3);
            } else jloc = p;
            outv[e] = f2bf(t[kc * 65 + jloc]);
        }
        *(u16x4*)(dst + (size_t)(c0 + kc) * rows + r0 + s * 8) = *(u16x4*)&outv[0];
        *(u16x4*)(dst + (size_t)(c0 + kc) * rows + r0 + s * 8 + 4) = *(u16x4*)&outv[4];
    }
}

// ---------------- MFMA GEMM: S += upw3 @ uc^T, split-K over blockIdx.z, bf16x3 when HAS_LO ----------------
template <int HAS_LO>
__global__ __launch_bounds__(TPB) void gemmS_mfma(
    const u16* __restrict__ Ah, const u16* __restrict__ Al,
    const u16* __restrict__ Bh, const u16* __restrict__ Bl,
    float* __restrict__ S, int n, int d, int ksplit) {
    __shared__ u16 sm[4 * 4096];
    u16* sAh = sm; u16* sAl = sm + 4096; u16* sBh = sm + 8192; u16* sBl = sm + 12288;
    int tid = threadIdx.x;
    int lane = tid & 63, wave = tid >> 6;
    int wm = wave >> 1, wn = wave & 1;
    int lrow = lane & 15, g = lane >> 4;
    int i0 = blockIdx.y * 64, j0 = blockIdx.x * 64;
    int kchunk = d / ksplit;
    int kbeg = blockIdx.z * kchunk;
    f32x4 acc[2][2];
    #pragma unroll
    for (int a = 0; a < 2; ++a)
        #pragma unroll
        for (int b = 0; b < 2; ++b) acc[a][b] = (f32x4){0.f, 0.f, 0.f, 0.f};

    for (int k0 = kbeg; k0 < kbeg + kchunk; k0 += 64) {
        #pragma unroll
        for (int it = 0; it < 2; ++it) {
            int id = tid + it * TPB;
            int row = id >> 3, slot = id & 7;
            int boff = (row * 128 + slot * 16) ^ ((row & 7) << 4);
            *(int4*)((char*)sAh + boff) = *(const int4*)(Ah + (size_t)(i0 + row) * d + k0 + slot * 8);
            *(int4*)((char*)sBh + boff) = *(const int4*)(Bh + (size_t)(j0 + row) * d + k0 + slot * 8);
            if (HAS_LO) {
                *(int4*)((char*)sAl + boff) = *(const int4*)(Al + (size_t)(i0 + row) * d + k0 + slot * 8);
                *(int4*)((char*)sBl + boff) = *(const int4*)(Bl + (size_t)(j0 + row) * d + k0 + slot * 8);
            }
        }
        __syncthreads();
        #pragma unroll
        for (int kk = 0; kk < 2; ++kk) {
            bf16x8 afh[2], bfh[2], afl[2], bfl[2];
            #pragma unroll
            for (int mr = 0; mr < 2; ++mr) {
                int row = wm * 32 + mr * 16 + lrow;
                int boff = (row * 128 + kk * 64 + g * 16) ^ ((row & 7) << 4);
                afh[mr] = *(const bf16x8*)((const char*)sAh + boff);
                if (HAS_LO) afl[mr] = *(const bf16x8*)((const char*)sAl + boff);
            }
            #pragma unroll
            for (int nr = 0; nr < 2; ++nr) {
                int row = wn * 32 + nr * 16 + lrow;
                int boff = (row * 128 + kk * 64 + g * 16) ^ ((row & 7) << 4);
                bfh[nr] = *(const bf16x8*)((const char*)sBh + boff);
                if (HAS_LO) bfl[nr] = *(const bf16x8*)((const char*)sBl + boff);
            }
            #pragma unroll
            for (int mr = 0; mr < 2; ++mr)
                #pragma unroll
                for (int nr = 0; nr < 2; ++nr) {
                    acc[mr][nr] = __builtin_amdgcn_mfma_f32_16x16x32_bf16(afh[mr], bfh[nr], acc[mr][nr], 0, 0, 0);
                    if (HAS_LO) {
                        acc[mr][nr] = __builtin_amdgcn_mfma_f32_16x16x32_bf16(afh[mr], bfl[nr], acc[mr][nr], 0, 0, 0);
                        acc[mr][nr] = __builtin_amdgcn_mfma_f32_16x16x32_bf16(afl[mr], bfh[nr], acc[mr][nr], 0, 0, 0);
                    }
                }
        }
        __syncthreads();
    }
    int crow = (lane >> 4) * 4;
    int ccol = lane & 15;
    #pragma unroll
    for (int mr = 0; mr < 2; ++mr) {
        #pragma unroll
        for (int nr = 0; nr < 2; ++nr) {
            int jc = j0 + wn * 32 + nr * 16 + ccol;
            #pragma unroll
            for (int jr = 0; jr < 4; ++jr) {
                int i = i0 + wm * 32 + mr * 16 + crow + jr;
                unsafeAtomicAdd(&S[(size_t)i * n + jc], acc[mr][nr][jr]);
            }
        }
    }
}

// ---------------- row softmax stats ----------------
__global__ __launch_bounds__(TPB) void row_stats_kernel(
    const float* __restrict__ S, float* __restrict__ rm, float* __restrict__ inv_rs, int n) {
    int row = blockIdx.x;
    const float* p = S + (size_t)row * n;
    float v[8];
    int cnt = 0;
    float mx = -INFINITY;
    for (int t = threadIdx.x; t < n; t += TPB) {
        v[cnt] = p[t];
        mx = fmaxf(mx, v[cnt]);
        ++cnt;
    }
    __shared__ float red[TPB];
    red[threadIdx.x] = mx;
    __syncthreads();
    for (int s = TPB / 2; s > 0; s >>= 1) {
        if (threadIdx.x < s) red[threadIdx.x] = fmaxf(red[threadIdx.x], red[threadIdx.x + s]);
        __syncthreads();
    }
    float gm = red[0];
    __syncthreads();
    float sum = 0.f;
    for (int u = 0; u < cnt; ++u) sum += __expf(v[u] - gm);
    red[threadIdx.x] = sum;
    __syncthreads();
    for (int s = TPB / 2; s > 0; s >>= 1) {
        if (threadIdx.x < s) red[threadIdx.x] += red[threadIdx.x + s];
        __syncthreads();
    }
    if (threadIdx.x == 0) { rm[row] = gm; inv_rs[row] = 1.f / red[0]; }
}

// ---------------- column softmax stats ----------------
__global__ __launch_bounds__(TPB) void col_stats_partial(
    const float* __restrict__ S, float* __restrict__ pm, float* __restrict__ ps,
    int n, int rows_per) {
    int col = blockIdx.x * TPB + threadIdx.x;
    int r0 = blockIdx.y * rows_per;
    float mx = -INFINITY, s = 0.f;
    for (int i = 0; i < rows_per; ++i) {
        float v = S[(size_t)(r0 + i) * n + col];
        if (v <= mx) {
            s += __expf(v - mx);
        } else {
            s = s * __expf(mx - v) + 1.f;
            mx = v;
        }
    }
    pm[(size_t)blockIdx.y * n + col] = mx;
    ps[(size_t)blockIdx.y * n + col] = s;
}

__global__ __launch_bounds__(TPB) void col_stats_merge(
    const float* __restrict__ pm, const float* __restrict__ ps,
    float* __restrict__ cm, float* __restrict__ inv_cs, int n, int chunks) {
    int col = blockIdx.x * TPB + threadIdx.x;
    float mx = -INFINITY;
    for (int c = 0; c < chunks; ++c) mx = fmaxf(mx, pm[(size_t)c * n + col]);
    float s = 0.f;
    for (int c = 0; c < chunks; ++c) s += ps[(size_t)c * n + col] * __expf(pm[(size_t)c * n + col] - mx);
    cm[col] = mx;
    inv_cs[col] = 1.f / s;
}

// ---------------- MFMA GEMM: a_alpha partials: out[z] = softmax_row(S[:, zchunk]) @ u_c[zchunk] ----------------
__global__ __launch_bounds__(TPB) void aalpha_mfma(
    const float* __restrict__ S, const float* __restrict__ rm, const float* __restrict__ irs,
    const u16* __restrict__ ucT, float* __restrict__ aalpha_part,
    const int* __restrict__ flagp, int m, int n, int d, int jsplit) {
    __shared__ u16 sA[4096];
    __shared__ u16 sB[4096];
    int fl = *flagp;
    int tid = threadIdx.x;
    int lane = tid & 63, wave = tid >> 6;
    int wm = wave >> 1, wn = wave & 1;
    int lrow = lane & 15, g = lane >> 4;
    int i0 = blockIdx.y * 64, kc0 = blockIdx.x * 64;
    int jchunk = n / jsplit;
    int jbeg = blockIdx.z * jchunk;
    float* outp = aalpha_part + (size_t)blockIdx.z * m * d;
    f32x4 acc[2][2];
    #pragma unroll
    for (int a = 0; a < 2; ++a)
        #pragma unroll
        for (int b = 0; b < 2; ++b) acc[a][b] = (f32x4){0.f, 0.f, 0.f, 0.f};

    for (int j0 = jbeg; j0 < jbeg + jchunk; j0 += 64) {
        #pragma unroll
        for (int it = 0; it < 4; ++it) {
            int id = tid + it * TPB;
            int row = id >> 4;
            int cq = id & 15;
            float4 sv = *(const float4*)(S + (size_t)(i0 + row) * n + j0 + cq * 4);
            float mi = rm[i0 + row], sc = irs[i0 + row];
            int p = fl ? (32 * (cq >> 3) + (cq & 3) * 8 + ((cq >> 2) & 1) * 4) : cq * 4;
            int boff = (row * 128 + p * 2) ^ ((row & 7) << 4);
            u16x4 pv = {f2bf(__expf(sv.x - mi) * sc), f2bf(__expf(sv.y - mi) * sc),
                        f2bf(__expf(sv.z - mi) * sc), f2bf(__expf(sv.w - mi) * sc)};
            *(u16x4*)((char*)sA + boff) = pv;
        }
        #pragma unroll
        for (int it = 0; it < 2; ++it) {
            int id = tid + it * TPB;
            int row = id >> 3, slot = id & 7;
            int boff = (row * 128 + slot * 16) ^ ((row & 7) << 4);
            *(int4*)((char*)sB + boff) = *(const int4*)(ucT + (size_t)(kc0 + row) * n + j0 + slot * 8);
        }
        __syncthreads();
        #pragma unroll
        for (int kk = 0; kk < 2; ++kk) {
            bf16x8 av[2], bv[2];
            #pragma unroll
            for (int mr = 0; mr < 2; ++mr) {
                int row = wm * 32 + mr * 16 + lrow;
                int boff = (row * 128 + kk * 64 + g * 16) ^ ((row & 7) << 4);
                av[mr] = *(const bf16x8*)((const char*)sA + boff);
            }
            #pragma unroll
            for (int nr = 0; nr < 2; ++nr) {
                int row = wn * 32 + nr * 16 + lrow;
                int boff = (row * 128 + kk * 64 + g * 16) ^ ((row & 7) << 4);
                bv[nr] = *(const bf16x8*)((const char*)sB + boff);
            }
            #pragma unroll
            for (int mr = 0; mr < 2; ++mr)
                #pragma unroll
                for (int nr = 0; nr < 2; ++nr)
                    acc[mr][nr] = __builtin_amdgcn_mfma_f32_16x16x32_bf16(av[mr], bv[nr], acc[mr][nr], 0, 0, 0);
        }
        __syncthreads();
    }
    int crow = (lane >> 4) * 4;
    int ccol = lane & 15;
    #pragma unroll
    for (int mr = 0; mr < 2; ++mr)
        #pragma unroll
        for (int nr = 0; nr < 2; ++nr) {
            int kc = kc0 + wn * 32 + nr * 16 + ccol;
            #pragma unroll
            for (int jr = 0; jr < 4; ++jr) {
                int i = i0 + wm * 32 + mr * 16 + crow + jr;
                outp[(size_t)i * d + kc] = acc[mr][nr][jr];
            }
        }
}

// ---------------- MFMA GEMM: a_beta partials: out[z] = softmax_col(S[zchunk,:])^T @ u_p[zchunk] ----------------
__global__ __launch_bounds__(TPB) void abeta_mfma(
    const float* __restrict__ S, const float* __restrict__ cm, const float* __restrict__ ics,
    const u16* __restrict__ upT, float* __restrict__ abeta_part,
    const int* __restrict__ flagp, int m, int n, int d, int isplit) {
    __shared__ u16 sA[4096];
    __shared__ u16 sB[4096];
    int fl = *flagp;
    int tid = threadIdx.x;
    int lane = tid & 63, wave = tid >> 6;
    int wm = wave >> 1, wn = wave & 1;
    int lrow = lane & 15, g = lane >> 4;
    int jb0 = blockIdx.y * 64, kc0 = blockIdx.x * 64;
    int ichunk = m / isplit;
    int ibeg = blockIdx.z * ichunk;
    float* outp = abeta_part + (size_t)blockIdx.z * n * d;
    f32x4 acc[2][2];
    #pragma unroll
    for (int a = 0; a < 2; ++a)
        #pragma unroll
        for (int b = 0; b < 2; ++b) acc[a][b] = (f32x4){0.f, 0.f, 0.f, 0.f};

    for (int i0 = ibeg; i0 < ibeg + ichunk; i0 += 64) {
        #pragma unroll
        for (int it = 0; it < 4; ++it) {
            int id = tid + it * TPB;
            int r = id >> 4;
            int cq = id & 15;
            float4 sv = *(const float4*)(S + (size_t)(i0 + r) * n + jb0 + cq * 4);
            float4 mj = *(const float4*)(cm + jb0 + cq * 4);
            float4 sj = *(const float4*)(ics + jb0 + cq * 4);
            int pi;
            if (fl) { int r5 = r & 31; pi = 32 * (r >> 5) + ((r5 >> 2) & 3) * 8 + (r5 >> 4) * 4 + (r5 & 3); }
            else pi = r;
            u16 v0 = f2bf(__expf(sv.x - mj.x) * sj.x);
            u16 v1 = f2bf(__expf(sv.y - mj.y) * sj.y);
            u16 v2 = f2bf(__expf(sv.z - mj.z) * sj.z);
            u16 v3 = f2bf(__expf(sv.w - mj.w) * sj.w);
            int j = cq * 4;
            *(u16*)((char*)sA + ((((j + 0) * 128) + pi * 2) ^ (((j + 0) & 7) << 4))) = v0;
            *(u16*)((char*)sA + ((((j + 1) * 128) + pi * 2) ^ (((j + 1) & 7) << 4))) = v1;
            *(u16*)((char*)sA + ((((j + 2) * 128) + pi * 2) ^ (((j + 2) & 7) << 4))) = v2;
            *(u16*)((char*)sA + ((((j + 3) * 128) + pi * 2) ^ (((j + 3) & 7) << 4))) = v3;
        }
        #pragma unroll
        for (int it = 0; it < 2; ++it) {
            int id = tid + it * TPB;
            int row = id >> 3, slot = id & 7;
            int boff = (row * 128 + slot * 16) ^ ((row & 7) << 4);
            *(int4*)((char*)sB + boff) = *(const int4*)(upT + (size_t)(kc0 + row) * m + i0 + slot * 8);
        }
        __syncthreads();
        #pragma unroll
        for (int kk = 0; kk < 2; ++kk) {
            bf16x8 av[2], bv[2];
            #pragma unroll
            for (int mr = 0; mr < 2; ++mr) {
                int row = wm * 32 + mr * 16 + lrow;
                int boff = (row * 128 + kk * 64 + g * 16) ^ ((row & 7) << 4);
                av[mr] = *(const bf16x8*)((const char*)sA + boff);
            }
            #pragma unroll
            for (int nr = 0; nr < 2; ++nr) {
                int row = wn * 32 + nr * 16 + lrow;
                int boff = (row * 128 + kk * 64 + g * 16) ^ ((row & 7) << 4);
                bv[nr] = *(const bf16x8*)((const char*)sB + boff);
            }
            #pragma unroll
            for (int mr = 0; mr < 2; ++mr)
                #pragma unroll
                for (int nr = 0; nr < 2; ++nr)
                    acc[mr][nr] = __builtin_amdgcn_mfma_f32_16x16x32_bf16(av[mr], bv[nr], acc[mr][nr], 0, 0, 0);
        }
        __syncthreads();
    }
    int crow = (lane >> 4) * 4;
    int ccol = lane & 15;
    #pragma unroll
    for (int mr = 0; mr < 2; ++mr)
        #pragma unroll
        for (int nr = 0; nr < 2; ++nr) {
            int kc = kc0 + wn * 32 + nr * 16 + ccol;
            #pragma unroll
            for (int jr = 0; jr < 4; ++jr) {
                int j = jb0 + wm * 32 + mr * 16 + crow + jr;
                outp[(size_t)j * d + kc] = acc[mr][nr][jr];
            }
        }
}

// ---------------- fused final dot, stage 1 (sums the z-partials inline) ----------------
__global__ __launch_bounds__(TPB) void final_stage1(
    const float* __restrict__ u_p, const float* __restrict__ u_c,
    const float* __restrict__ aa0, const float* __restrict__ aa1,
    const float* __restrict__ ab0, const float* __restrict__ ab1,
    const float* __restrict__ W, float* __restrict__ partials, int n, int d) {
    size_t total = (size_t)n * d / 4;
    float acc = 0.f;
    for (size_t q = (size_t)blockIdx.x * TPB + threadIdx.x; q < total;
         q += (size_t)gridDim.x * TPB) {
        size_t e = q * 4;
        int i = (int)(e / d);
        int k = (int)(e % d);
        size_t base = (size_t)i * d + k;
        float4 up = *(const float4*)(u_p + base);
        float4 a0 = *(const float4*)(aa0 + base);
        float4 a1 = *(const float4*)(aa1 + base);
        float4 uc = *(const float4*)(u_c + base);
        float4 b0 = *(const float4*)(ab0 + base);
        float4 b1 = *(const float4*)(ab1 + base);
        float4 aa = {a0.x + a1.x, a0.y + a1.y, a0.z + a1.z, a0.w + a1.w};
        float4 ab = {b0.x + b1.x, b0.y + b1.y, b0.z + b1.z, b0.w + b1.w};
        const float* wr = W + (size_t)i * 4 * d;
        float4 w0 = *(const float4*)(wr + k);
        float4 w1 = *(const float4*)(wr + d + k);
        float4 w2 = *(const float4*)(wr + 2 * d + k);
        float4 w3 = *(const float4*)(wr + 3 * d + k);
        acc += up.x * w0.x + aa.x * (w1.x + up.x * w2.x) + uc.x * ab.x * w3.x;
        acc += up.y * w0.y + aa.y * (w1.y + up.y * w2.y) + uc.y * ab.y * w3.y;
        acc += up.z * w0.z + aa.z * (w1.z + up.z * w2.z) + uc.z * ab.z * w3.z;
        acc += up.w * w0.w + aa.w * (w1.w + up.w * w2.w) + uc.w * ab.w * w3.w;
    }
    __shared__ float red[TPB];
    red[threadIdx.x] = acc;
    __syncthreads();
    for (int s = TPB / 2; s > 0; s >>= 1) {
        if (threadIdx.x < s) red[threadIdx.x] += red[threadIdx.x + s];
        __syncthreads();
    }
    if (threadIdx.x == 0) partials[blockIdx.x] = red[0];
}

__global__ __launch_bounds__(TPB) void final_stage2(
    const float* __restrict__ partials, int np, const float* __restrict__ bias,
    float* __restrict__ out) {
    double acc = 0.0;
    for (int t = threadIdx.x; t < np; t += TPB) acc += (double)partials[t];
    __shared__ double red[TPB];
    red[threadIdx.x] = acc;
    __syncthreads();
    for (int s = TPB / 2; s > 0; s >>= 1) {
        if (threadIdx.x < s) red[threadIdx.x] += red[threadIdx.x + s];
        __syncthreads();
    }
    if (threadIdx.x == 0) {
        double v = red[0] + (double)bias[0];
        out[0] = (float)(v > 0.0 ? v : 0.0);
    }
}

extern "C" void kernel_launch(void* const* d_in, const int* in_sizes, int n_in,
                              void* d_out, int out_size, void* d_ws, size_t ws_size,
                              hipStream_t stream) {
    const float* u_p = (const float*)d_in[0];
    const float* u_c = (const float*)d_in[1];
    const float* w_a = (const float*)d_in[2];
    const float* ffn_w = (const float*)d_in[3];
    const float* ffn_b = (const float*)d_in[4];
    float* out = (float*)d_out;

    int d = in_sizes[2] / 3;   // 2048
    int m = in_sizes[0] / d;   // 1024
    int n = in_sizes[1] / d;   // 1024
    const int CHUNKS = 64;
    const int NBLK_FINAL = 2048;
    const int KSPLIT = 4;      // gemmS:   1024 blocks = 4/CU
    const int JSPLIT = 2;      // aalpha:  1024 blocks = 4/CU
    const int ISPLIT = 2;      // abeta:   1024 blocks = 4/CU

    size_t md = (size_t)m * d, nd = (size_t)n * d, mn = (size_t)m * n;

    float* ws = (float*)d_ws;
    float* r = ws;                      // m
    float* c = r + m;                   // n
    float* rm = c + n;                  // m
    float* inv_rs = rm + m;             // m
    float* cm = inv_rs + m;             // n
    float* inv_cs = cm + n;             // n
    float* pm = inv_cs + n;             // CHUNKS*n
    float* ps = pm + (size_t)CHUNKS * n;
    float* partials = ps + (size_t)CHUNKS * n;  // NBLK_FINAL
    int* flagp = (int*)(partials + NBLK_FINAL);
    float* S = (float*)(flagp + 16);
    float* aalpha = S + mn;             // JSPLIT * md  (partials)
    float* abeta = aalpha + (size_t)JSPLIT * md;  // ISPLIT * nd (partials)
    u16* upw3_hi = (u16*)(abeta + (size_t)ISPLIT * nd);
    u16* uc_hi = upw3_hi + md;
    u16* ucT_hi = uc_hi + nd;
    u16* upT_hi = ucT_hi + nd;
    u16* upw3_lo = upT_hi + md;
    u16* uc_lo = upw3_lo + md;
    size_t need_full = (size_t)((char*)(uc_lo + nd) - (char*)d_ws);
    int has_lo = ws_size >= need_full ? 1 : 0;

    probe_kernel<<<1, 64, 0, stream>>>(flagp);
    bias_kernel<<<m + n, TPB, 0, stream>>>(u_p, u_c, w_a, r, c, m, n, d);
    convert_kernel<<<2048, TPB, 0, stream>>>(u_p, u_c, w_a, upw3_hi, upw3_lo,
                                             uc_hi, uc_lo, flagp, m, n, d, has_lo);
    dim3 gtc(d / 64, n / 64);
    transpose_kernel<<<gtc, TPB, 0, stream>>>(u_c, ucT_hi, flagp, n, d);
    dim3 gtp(d / 64, m / 64);
    transpose_kernel<<<gtp, TPB, 0, stream>>>(u_p, upT_hi, flagp, m, d);

    initS_kernel<<<(m * (n / 4) + TPB - 1) / TPB, TPB, 0, stream>>>(r, c, S, m, n);

    dim3 gS(n / 64, m / 64, KSPLIT);
    if (has_lo)
        gemmS_mfma<1><<<gS, TPB, 0, stream>>>(upw3_hi, upw3_lo, uc_hi, uc_lo, S, n, d, KSPLIT);
    else
        gemmS_mfma<0><<<gS, TPB, 0, stream>>>(upw3_hi, upw3_lo, uc_hi, uc_lo, S, n, d, KSPLIT);

    row_stats_kernel<<<m, TPB, 0, stream>>>(S, rm, inv_rs, n);
    dim3 gCP(n / TPB, CHUNKS);
    col_stats_partial<<<gCP, TPB, 0, stream>>>(S, pm, ps, n, m / CHUNKS);
    col_stats_merge<<<n / TPB, TPB, 0, stream>>>(pm, ps, cm, inv_cs, n, CHUNKS);

    dim3 gA(d / 64, m / 64, JSPLIT);
    aalpha_mfma<<<gA, TPB, 0, stream>>>(S, rm, inv_rs, ucT_hi, aalpha, flagp, m, n, d, JSPLIT);
    dim3 gB(d / 64, n / 64, ISPLIT);
    abeta_mfma<<<gB, TPB, 0, stream>>>(S, cm, inv_cs, upT_hi, abeta, flagp, m, n, d, ISPLIT);

    final_stage1<<<NBLK_FINAL, TPB, 0, stream>>>(u_p, u_c, aalpha, aalpha + md,
                                                 abeta, abeta + nd, ffn_w,
                                                 partials, n, d);
    final_stage2<<<1, TPB, 0, stream>>>(partials, NBLK_FINAL, ffn_b, out);

    (void)out_size; (void)n_in;
}